// Round 2
// baseline (439.420 us; speedup 1.0000x reference)
//
#include <hip/hip_runtime.h>
#include <math.h>

// VectorExpansion: out[l, p, n] = sin(pi*x*n)/max(r,eps) * fc(r) * sqrt(2/rc) * x^l
// x = r/rc, rc=5, n=1..8, l=0..3.  fp32 in / fp32 out.
//
// R7 = R6 with the nontemporal-store type fixed (HIP float4 is a class type;
// __builtin_nontemporal_store needs a native clang vector).
//
// Structure (post-mortem R5: split zero-fill + sparse pass measured 332 us,
// 6.6x off the ~50 us traffic roofline; the split writes the same 256 MiB the
// fused kernel would, plus a second launch/serialization point. Harness's own
// fillBufferAligned dispatches prove 6.3-6.5 TB/s is reachable this session.):
//   Single branchless dense pass. Every lane computes its pair distance; pref
//   select()s to exactly 0.0 outside the cutoff, so out-of-range rows stream
//   zeros through the SAME 8 float4 nontemporal stores as in-range rows.
//   No divergence, no second kernel, 256 MiB written exactly once.
//   Traffic: 48 MB read (pairs/shifts/structure_pairs; positions+cells are
//   L2-resident) + 256 MiB write  ->  ~50 us roofline at 6.3 TB/s.

#define RC_INV 0.2f
#define NORM 0.6324555320336759f  /* sqrt(2/5) */

typedef float f32x4 __attribute__((ext_vector_type(4)));

__global__ __launch_bounds__(256) void ve_dense(
    const float* __restrict__ positions,        // [N,3] fp32
    const float* __restrict__ cells,            // [S,3,3] fp32
    const int* __restrict__ cell_shifts,        // [P,3]
    const int* __restrict__ pairs,              // [P,2]
    const int* __restrict__ structure_pairs,    // [P]
    const int* __restrict__ structure_offsets,  // [S]
    f32x4* __restrict__ out4,                   // [4,P,8] fp32 viewed as f32x4
    int P)
{
    const int p = blockIdx.x * blockDim.x + threadIdx.x;
    if (p >= P) return;

    const int s   = structure_pairs[p];
    const int off = structure_offsets[s];       // S=32 table, L1-resident
    const int2 pr = ((const int2*)pairs)[p];
    const int ia = 3 * (off + pr.x);
    const int ja = 3 * (off + pr.y);

    const float shx = (float)cell_shifts[3*p + 0];
    const float shy = (float)cell_shifts[3*p + 1];
    const float shz = (float)cell_shifts[3*p + 2];

    const float* C = cells + 9*s;               // row-major [c][d], L1-resident
    const float vx = positions[ja+0] - positions[ia+0] + shx*C[0] + shy*C[3] + shz*C[6];
    const float vy = positions[ja+1] - positions[ia+1] + shx*C[1] + shy*C[4] + shz*C[7];
    const float vz = positions[ja+2] - positions[ia+2] + shx*C[2] + shy*C[5] + shz*C[8];

    const float d2 = vx*vx + vy*vy + vz*vz + 1e-12f;
    const float r  = __builtin_amdgcn_sqrtf(d2);
    const float x  = r * RC_INV;
    const float xa = fminf(x, 1.0f);            // clamp for trig; pref zeroes x>=1 lanes

    // sin(pi*xa), cos(pi*xa) via HW trig (arg in revolutions; xa in [0,1] so
    // 0.5*xa in [0,0.5] needs no range reduction).
    const float s1 = __builtin_amdgcn_sinf(0.5f * xa);
    const float c1 = __builtin_amdgcn_cosf(0.5f * xa);
    const float fc = 0.5f * (c1 + 1.0f);
    // Exact 0 outside cutoff (matches reference's where()) -> zero rows stream
    // through the same stores; no branch, no divergence.
    const float pref = (x < 1.0f) ? fc * NORM * __builtin_amdgcn_rcpf(r) : 0.0f;

    // sin(n*pi*xa) by Chebyshev recurrence: s_{n+1} = 2*cos(pi*xa)*s_n - s_{n-1}
    float b[8];
    {
        float sm1 = 0.0f, sn = s1;
        const float twoc = 2.0f * c1;
        #pragma unroll
        for (int n = 0; n < 8; ++n) {
            b[n] = pref * sn;
            const float nxt = twoc * sn - sm1;
            sm1 = sn; sn = nxt;
        }
    }

    // out flat (l,p,n) = l*P*8 + p*8 + n  ->  f32x4 slot (l*P+p)*2 + {0,1}
    // Per-wave per-l: 64 lanes x 32 B = contiguous 2 KB, fully coalesced.
    float xl = 1.0f;
    #pragma unroll
    for (int l = 0; l < 4; ++l) {
        const long long base = 2LL * (1LL*l*P + p);
        f32x4 lo = { b[0]*xl, b[1]*xl, b[2]*xl, b[3]*xl };
        f32x4 hi = { b[4]*xl, b[5]*xl, b[6]*xl, b[7]*xl };
        __builtin_nontemporal_store(lo, &out4[base + 0]);
        __builtin_nontemporal_store(hi, &out4[base + 1]);
        xl *= xa;                               // x^l; pref==0 already zeroes x>=1 lanes
    }
}

extern "C" void kernel_launch(void* const* d_in, const int* in_sizes, int n_in,
                              void* d_out, int out_size, void* d_ws, size_t ws_size,
                              hipStream_t stream) {
    const float* positions         = (const float*)d_in[0];
    const float* cells             = (const float*)d_in[1];
    const int*   cell_shifts       = (const int*)d_in[3];
    const int*   pairs             = (const int*)d_in[5];
    const int*   structure_pairs   = (const int*)d_in[7];
    const int*   structure_offsets = (const int*)d_in[8];

    const int P = in_sizes[7];          // structure_pairs is [P]
    const int block = 256;

    ve_dense<<<(P + block - 1) / block, block, 0, stream>>>(
        positions, cells, cell_shifts, pairs,
        structure_pairs, structure_offsets, (f32x4*)d_out, P);
}

// Round 3
// 351.377 us; speedup vs baseline: 1.2506x; 1.2506x over previous
//
#include <hip/hip_runtime.h>
#include <math.h>

// VectorExpansion: out[l, p, n] = sin(pi*x*n)/max(r,eps) * fc(r) * sqrt(2/rc) * x^l
// x = r/rc, rc=5, n=1..8, l=0..3.  fp32 in / fp32 out.
//
// R8 (post-mortem R7: WRITE_SIZE was 521 MB = 1.94x the 256 MiB output.
// Cause: 32 B/lane output with 16 B max store width -> within each store
// instruction lanes wrote at stride 32 B, half-covering every 64 B sector;
// NT streaming flushed partial sectors before the companion store merged ->
// every line written to HBM twice. 2.7 TB/s, VALUBusy 2.5%.):
//   TWO THREADS PER PAIR. Thread gid -> pair p=gid>>1, half h=gid&1.
//   Each thread duplicates the cheap trig chain (compute is 2.5% busy) and
//   stores exactly one f32x4 per l at slot 2*l*P + gid: consecutive lanes ->
//   consecutive 16 B slots -> every store instruction is a dense 1 KB block
//   of full 64 B sectors. Adjacent lane pairs load identical pair data
//   (coalesced, L1-served), so HBM fetch is unchanged.
//   Traffic floor: 256 MiB write + ~48 MB read -> ~50 us at 6.3 TB/s.

#define RC_INV 0.2f
#define NORM 0.6324555320336759f  /* sqrt(2/5) */

typedef float f32x4 __attribute__((ext_vector_type(4)));

__global__ __launch_bounds__(256) void ve_dense2(
    const float* __restrict__ positions,        // [N,3] fp32
    const float* __restrict__ cells,            // [S,3,3] fp32
    const int* __restrict__ cell_shifts,        // [P,3]
    const int* __restrict__ pairs,              // [P,2]
    const int* __restrict__ structure_pairs,    // [P]
    const int* __restrict__ structure_offsets,  // [S]
    f32x4* __restrict__ out4,                   // [4,P,8] fp32 viewed as f32x4
    int P)
{
    const int gid = blockIdx.x * blockDim.x + threadIdx.x;
    if (gid >= 2 * P) return;
    const int p = gid >> 1;                     // pair index
    const int h = gid & 1;                      // which f32x4 half (n 0-3 or 4-7)

    const int s   = structure_pairs[p];
    const int off = structure_offsets[s];       // S=32 table, L1-resident
    const int2 pr = ((const int2*)pairs)[p];
    const int ia = 3 * (off + pr.x);
    const int ja = 3 * (off + pr.y);

    const float shx = (float)cell_shifts[3*p + 0];
    const float shy = (float)cell_shifts[3*p + 1];
    const float shz = (float)cell_shifts[3*p + 2];

    const float* C = cells + 9*s;               // row-major [c][d], L1-resident
    const float vx = positions[ja+0] - positions[ia+0] + shx*C[0] + shy*C[3] + shz*C[6];
    const float vy = positions[ja+1] - positions[ia+1] + shx*C[1] + shy*C[4] + shz*C[7];
    const float vz = positions[ja+2] - positions[ia+2] + shx*C[2] + shy*C[5] + shz*C[8];

    const float d2 = vx*vx + vy*vy + vz*vz + 1e-12f;
    const float r  = __builtin_amdgcn_sqrtf(d2);
    const float x  = r * RC_INV;
    const float xa = fminf(x, 1.0f);            // clamp for trig; pref zeroes x>=1 lanes

    // sin(pi*xa), cos(pi*xa) via HW trig (arg in revolutions; xa in [0,1] so
    // 0.5*xa in [0,0.5] needs no range reduction).
    const float s1 = __builtin_amdgcn_sinf(0.5f * xa);
    const float c1 = __builtin_amdgcn_cosf(0.5f * xa);
    const float fc = 0.5f * (c1 + 1.0f);
    // Exact 0 outside cutoff (matches reference's where()) -> zero rows stream
    // through the same stores; no branch, no divergence.
    const float pref = (x < 1.0f) ? fc * NORM * __builtin_amdgcn_rcpf(r) : 0.0f;

    // sin(n*pi*xa) by Chebyshev recurrence: s_{n+1} = 2*cos(pi*xa)*s_n - s_{n-1}
    float b[8];
    {
        float sm1 = 0.0f, sn = s1;
        const float twoc = 2.0f * c1;
        #pragma unroll
        for (int n = 0; n < 8; ++n) {
            b[n] = pref * sn;
            const float nxt = twoc * sn - sm1;
            sm1 = sn; sn = nxt;
        }
    }

    // Select this thread's half (static indexing only — no scratch).
    const float e0 = h ? b[4] : b[0];
    const float e1 = h ? b[5] : b[1];
    const float e2 = h ? b[6] : b[2];
    const float e3 = h ? b[7] : b[3];

    // out flat (l,p,n): f32x4 slot = 2*l*P + 2*p + h = 2*l*P + gid.
    // Per instruction: 64 lanes x 16 B consecutive = dense 1 KB block.
    float xl = 1.0f;
    #pragma unroll
    for (int l = 0; l < 4; ++l) {
        const long long slot = 2LL * l * P + gid;
        f32x4 v = { e0*xl, e1*xl, e2*xl, e3*xl };
        __builtin_nontemporal_store(v, &out4[slot]);
        xl *= xa;                               // x^l; pref==0 already zeroes x>=1 lanes
    }
}

extern "C" void kernel_launch(void* const* d_in, const int* in_sizes, int n_in,
                              void* d_out, int out_size, void* d_ws, size_t ws_size,
                              hipStream_t stream) {
    const float* positions         = (const float*)d_in[0];
    const float* cells             = (const float*)d_in[1];
    const int*   cell_shifts       = (const int*)d_in[3];
    const int*   pairs             = (const int*)d_in[5];
    const int*   structure_pairs   = (const int*)d_in[7];
    const int*   structure_offsets = (const int*)d_in[8];

    const int P = in_sizes[7];          // structure_pairs is [P]
    const int block = 256;
    const long long threads = 2LL * P;  // two threads per pair

    ve_dense2<<<(int)((threads + block - 1) / block), block, 0, stream>>>(
        positions, cells, cell_shifts, pairs,
        structure_pairs, structure_offsets, (f32x4*)d_out, P);
}